// Round 18
// baseline (183.142 us; speedup 1.0000x reference)
//
#include <hip/hip_runtime.h>
#include <hip/hip_bf16.h>

// ---------------------------------------------------------------------------
// MultiHeadAttention: x(B,T,C) fp32 -> out(B,T,C) fp32
// B=4 T=2048 C=1024 H=16 D=64. Internally bf16 MFMA with fp32 accumulation.
// Pipeline: convert -> fused QKV GEMM -> pipelined causal flash attn -> out GEMM.
// ---------------------------------------------------------------------------

#define B_  4
#define T_  2048
#define C_  1024
#define H_  16
#define D_  64
#define M_  (B_*T_)   // 8192 rows for the projection GEMMs

#define LOG2E 1.4426950408889634f

using bf16x8 = __attribute__((ext_vector_type(8))) short;
using f32x4  = __attribute__((ext_vector_type(4))) float;
using u16x4  = __attribute__((ext_vector_type(4))) unsigned short;

__device__ __forceinline__ unsigned short f2bf(float f) {
  union { float f; unsigned u; } cv; cv.f = f;
  unsigned u = cv.u;
  u += 0x7fffu + ((u >> 16) & 1u);   // RNE (inputs are finite)
  return (unsigned short)(u >> 16);
}

// pack two f32 -> one dword of 2 bf16 (RNE), single VALU op
__device__ __forceinline__ unsigned cvt_pk_bf16(float lo, float hi) {
  unsigned r;
  asm("v_cvt_pk_bf16_f32 %0, %1, %2" : "=v"(r) : "v"(lo), "v"(hi));
  return r;
}

__device__ __forceinline__ float exp2fast(float x) {
#if __has_builtin(__builtin_amdgcn_exp2f)
  return __builtin_amdgcn_exp2f(x);
#else
  return exp2f(x);
#endif
}

__device__ __forceinline__ void lds_load16(void* lds, const void* g) {
  __builtin_amdgcn_global_load_lds(
      (const __attribute__((address_space(1))) unsigned int*)g,
      (__attribute__((address_space(3))) unsigned int*)lds,
      16, 0, 0);
}

// ---------------------------------------------------------------------------
// Kernel 1: x fp32 -> bf16 (8 elems/thread, vectorized)
// ---------------------------------------------------------------------------
__global__ __launch_bounds__(256) void conv_x_kernel(
    const float* __restrict__ x, unsigned short* __restrict__ xb) {
  int i = blockIdx.x * 256 + threadIdx.x;      // group of 8 elements
  const float4* xv = (const float4*)x;
  float4 a = xv[i * 2 + 0];
  float4 b = xv[i * 2 + 1];
  using u16x8 = __attribute__((ext_vector_type(8))) unsigned short;
  u16x8 o;
  o[0]=f2bf(a.x); o[1]=f2bf(a.y); o[2]=f2bf(a.z); o[3]=f2bf(a.w);
  o[4]=f2bf(b.x); o[5]=f2bf(b.y); o[6]=f2bf(b.z); o[7]=f2bf(b.w);
  *(u16x8*)&xb[(size_t)i * 8] = o;
}

// ---------------------------------------------------------------------------
// Kernel 2: 4 weights (K x N fp32, applied as x@W) -> W^T (N x K bf16), batched
// ---------------------------------------------------------------------------
__global__ __launch_bounds__(256) void conv_wt_kernel(
    const float* __restrict__ W0, const float* __restrict__ W1,
    const float* __restrict__ W2, const float* __restrict__ W3,
    unsigned short* __restrict__ WT) {
  __shared__ float tile[64][65];
  const float* W = (blockIdx.z == 0) ? W0 : (blockIdx.z == 1) ? W1
                 : (blockIdx.z == 2) ? W2 : W3;
  unsigned short* o = WT + (size_t)blockIdx.z * C_ * C_;
  const int k0 = blockIdx.y * 64, n0 = blockIdx.x * 64;
  const int tr = threadIdx.x >> 6;   // 0..3
  const int tc = threadIdx.x & 63;   // 0..63
#pragma unroll
  for (int i = 0; i < 16; ++i) {
    int k = tr + i * 4;
    tile[k][tc] = W[(size_t)(k0 + k) * C_ + n0 + tc];
  }
  __syncthreads();
#pragma unroll
  for (int i = 0; i < 16; ++i) {
    int n = tr + i * 4;
    o[(size_t)(n0 + n) * C_ + k0 + tc] = f2bf(tile[tc][n]);
  }
}

// ---------------------------------------------------------------------------
// Kernel 3: GEMM  C[M x N] = A[M x K] * BT[N x K]^T
// 128x128 tile, BK=32, 4 waves (2x2 of 64x64), global_load_lds staging.
// XCD-aware block swizzle (R13-proven): bid -> xcd=bid&7; bm=xcd+8*(i&7),
// bn=i>>3.
// R18: MFMA operands SWAPPED (acc = mfma(bfr, af, acc)) -> lane (fr,fq)
// holds C[m=tile+fr][n=tile+fq*4+r], 4 CONSECUTIVE n per lane:
//   EPI0 (QKV): one 8B uint2 store + 2 cvt_pk per fragment (was 4 scalar
//   b16 stores + 4 f2bf). The 4 n's share mat/h (ni*16+fq*4+3 <= 63).
//   EPI1 (out): one float4 store + float4 bias load (was 4 scalar f32).
// A/B fragment reads, staging, K-loop identical to the passing R17.
// ---------------------------------------------------------------------------
template <int EPI>
__global__ __launch_bounds__(256) void gemm128(
    const unsigned short* __restrict__ A, const unsigned short* __restrict__ BT,
    void* __restrict__ out, const float* __restrict__ bias, int K) {
  __shared__ unsigned short As[128][32];   // 8 KB
  __shared__ unsigned short Bs[128][32];   // 8 KB

  const int tid  = threadIdx.x;
  const int wid  = tid >> 6, lane = tid & 63;
  const int wr   = wid >> 1, wc = wid & 1;
  const int fr   = lane & 15, fq = lane >> 4;
  const int bid  = blockIdx.y * gridDim.x + blockIdx.x;   // dispatch-linear
  const int xcd  = bid & 7, ii = bid >> 3;
  const int bm   = xcd + 8 * (ii & 7);     // 0..63
  const int bn   = ii >> 3;                // 0..gridDim.x-1

  const unsigned short* aP = A  + (size_t)(bm * 128 + wid * 32 + (lane >> 2)) * K + (lane & 3) * 8;
  const unsigned short* bP = BT + (size_t)(bn * 128 + wid * 32 + (lane >> 2)) * K + (lane & 3) * 8;
  unsigned short* asB = &As[wid * 32][0];
  unsigned short* bsB = &Bs[wid * 32][0];

  f32x4 acc[4][4] = {};

  for (int k0 = 0; k0 < K; k0 += 32) {
    lds_load16(asB,           aP + k0);
    lds_load16(asB + 16 * 32, aP + (size_t)16 * K + k0);
    lds_load16(bsB,           bP + k0);
    lds_load16(bsB + 16 * 32, bP + (size_t)16 * K + k0);
    __syncthreads();

    bf16x8 af[4], bfr[4];
#pragma unroll
    for (int mi = 0; mi < 4; ++mi)
      af[mi] = *(const bf16x8*)&As[wr * 64 + mi * 16 + fr][fq * 8];
#pragma unroll
    for (int ni = 0; ni < 4; ++ni)
      bfr[ni] = *(const bf16x8*)&Bs[wc * 64 + ni * 16 + fr][fq * 8];
#pragma unroll
    for (int mi = 0; mi < 4; ++mi)
#pragma unroll
      for (int ni = 0; ni < 4; ++ni)
        acc[mi][ni] = __builtin_amdgcn_mfma_f32_16x16x32_bf16(
            bfr[ni], af[mi], acc[mi][ni], 0, 0, 0);   // SWAPPED: C^T layout
    __syncthreads();
  }

  if (EPI == 0) {
    // fused QKV: lane holds m = ...+fr, n = n0..n0+3 (consecutive).
    // n -> matrix (Q/K/V), head, d. Q scaled by log2(e)/sqrt(D).
    unsigned short* o = (unsigned short*)out;
#pragma unroll
    for (int mi = 0; mi < 4; ++mi) {
      int m  = bm * 128 + wr * 64 + mi * 16 + fr;
      int b  = m >> 11;          // T=2048
      int t0 = m & 2047;
#pragma unroll
      for (int ni = 0; ni < 4; ++ni) {
        int n0 = bn * 128 + wc * 64 + ni * 16 + fq * 4;
        int mat = n0 >> 10;
        int nc  = n0 & 1023;
        int h = nc >> 6, d0 = nc & 63;   // d0 4-aligned; all 4 share mat,h
        float sc_ = (mat == 0) ? (0.125f * LOG2E) : 1.0f;
        size_t addr = (size_t)mat * ((size_t)M_ * C_) +
                      ((size_t)(b * H_ + h) << 17) + (size_t)t0 * D_ + d0;
        uint2 pk;
        pk.x = cvt_pk_bf16(acc[mi][ni][0] * sc_, acc[mi][ni][1] * sc_);
        pk.y = cvt_pk_bf16(acc[mi][ni][2] * sc_, acc[mi][ni][3] * sc_);
        *(uint2*)&o[addr] = pk;
      }
    }
  } else {
    float* o = (float*)out;
#pragma unroll
    for (int mi = 0; mi < 4; ++mi) {
      int m = bm * 128 + wr * 64 + mi * 16 + fr;
#pragma unroll
      for (int ni = 0; ni < 4; ++ni) {
        int n0 = bn * 128 + wc * 64 + ni * 16 + fq * 4;
        float4 bv = *(const float4*)&bias[n0];
        float4 ov;
        ov.x = acc[mi][ni][0] + bv.x;
        ov.y = acc[mi][ni][1] + bv.y;
        ov.z = acc[mi][ni][2] + bv.z;
        ov.w = acc[mi][ni][3] + bv.w;
        *(float4*)&o[(size_t)m * C_ + n0] = ov;
      }
    }
  }
}

// ---------------------------------------------------------------------------
// Kernel 4: pipelined causal flash attention, 8 WAVES (512 thr), QBLK=256,
// KVBLK=64, no P-LDS. (R17-proven, unchanged.)
// K/V double-buffered, ONE barrier/step, stage-to-regs right after the
// barrier, LDS-write after compute into buf[cur^1]; defer-max rescale;
// K rows staged PERMUTED (row l(g) = g5 g2 g4g3 g1g0) so packed P dwords
// are exactly the PV B-fragments (P never touches LDS); lane-partial l;
// staging role-split (waves 0-3 stage V, waves 4-7 stage K); no skips.
// Grid 512, LPT (qt=7-(j>>3)), head-per-XCD swizzle.
// ---------------------------------------------------------------------------
#define KSTR 72
__global__ __launch_bounds__(512) void attn_kernel(
    const unsigned short* __restrict__ Qg, const unsigned short* __restrict__ Kg,
    const unsigned short* __restrict__ Vg, unsigned short* __restrict__ ctx) {
  __shared__ __align__(16) unsigned short Ks[2][64][KSTR];    // [buf][kv'][d]
  __shared__ __align__(16) unsigned short VTs[2][64][KSTR];   // [buf][d][kv]

  const int tid = threadIdx.x, wid = tid >> 6, lane = tid & 63;
  const int fr = lane & 15, fq = lane >> 4;

  const int bid = blockIdx.x;
  const int xcd = bid & 7, j = bid >> 3;        // j in 0..63
  const int bh = xcd * 8 + (j & 7);             // 8 heads per XCD (L2 locality)
  const int qt = 7 - (j >> 3);                  // q-tile 0..7, longest first
  const int b = bh >> 4, h = bh & 15;
  const size_t base = (size_t)bh * (T_ * D_);

  // Staging roles: waves 0-3 (tid<256) stage V; waves 4-7 stage K.
  const int vc = (tid & 255) >> 5, vr_ = tid & 31;
  const int kt = tid & 255, ksr = kt >> 2, ksc = kt & 3;
  const int kpr = ((ksr >> 5) & 1) * 32 + ((ksr >> 2) & 1) * 16 +
                  ((ksr >> 3) & 3) * 4 + (ksr & 3);
  const unsigned short* Kptr = Kg + base + (size_t)ksr * D_ + ksc * 8;
  const unsigned short* Vptr = Vg + base + (size_t)(2 * vr_) * D_ + vc * 8;

  int4 sa_, sb_;    // staging payload (role-dependent)
  auto stage_load = [&](int kv) {
    if (wid < 4) {  // V role
      const unsigned short* vp = Vptr + (size_t)kv * D_;
      sa_ = *(const int4*)vp;          // kv row 2vr_
      sb_ = *(const int4*)(vp + D_);   // kv row 2vr_+1
    } else {        // K role
      const unsigned short* kp = Kptr + (size_t)kv * D_;
      sa_ = *(const int4*)kp;
      sb_ = *(const int4*)(kp + 32);
    }
  };
  auto stage_write = [&](int nb) {
    if (wid < 4) {  // V: packed kv-pair transpose writes
      const unsigned short* pa = (const unsigned short*)&sa_;
      const unsigned short* pb = (const unsigned short*)&sb_;
#pragma unroll
      for (int i = 0; i < 8; ++i) {
        unsigned w = (unsigned)pa[i] | ((unsigned)pb[i] << 16);
        *(unsigned*)&VTs[nb][vc * 8 + i][2 * vr_] = w;
      }
    } else {        // K: permuted-row b128 writes
      *(int4*)&Ks[nb][kpr][ksc * 8]       = sa_;
      *(int4*)&Ks[nb][kpr][(ksc + 4) * 8] = sb_;
    }
  };

  stage_load(0);
  stage_write(0);           // tile 0 -> buf 0 (visible after first barrier)

  const int qbase = qt * 256;
  const int qrow = qbase + wid * 32;    // wave's first q row

  bf16x8 qf[2][2];          // [subtile][t]
#pragma unroll
  for (int x = 0; x < 2; ++x)
#pragma unroll
    for (int t = 0; t < 2; ++t)
      qf[x][t] = *(const bf16x8*)
          &Qg[base + (size_t)(qrow + 16 * x + fr) * D_ + t * 32 + fq * 8];

  f32x4 acc[2][4] = {};     // [subtile][d-tile]; O^T: q=row+fr, d=dt*16+fq*4+r
  float m_run[2] = {-__builtin_inff(), -__builtin_inff()};
  float l_run[2] = {0.f, 0.f};   // lane-partial; cross-fq reduced at finalize

  const int nsteps = 4 * qt + 4;   // kv tiles of 64: 0 .. qbase+192
  int kv0 = 0;
  for (int s = 0; s < nsteps; ++s) {
    const int  cur = s & 1;
    const bool have_next = (s + 1 < nsteps);

    __syncthreads();                              // buf[cur] ready; buf[cur^1] free
    if (have_next) stage_load(kv0 + 64);          // prefetch to regs (T14)

    // ---- K fragments (shared by both subtiles; data permuted at staging) ----
    bf16x8 kf[8];
#pragma unroll
    for (int nt = 0; nt < 4; ++nt)
#pragma unroll
      for (int t = 0; t < 2; ++t)
        kf[nt * 2 + t] = *(const bf16x8*)&Ks[cur][nt * 16 + fr][t * 32 + fq * 8];

    // ---- per-subtile: S^T = K Q^T, softmax, P packed in registers ----
    bf16x8 pf[2][2];        // [subtile][t] PV B-fragments, lane-local
#pragma unroll
    for (int x = 0; x < 2; ++x) {
      f32x4 sv[4];
      __builtin_amdgcn_s_setprio(1);
#pragma unroll
      for (int nt = 0; nt < 4; ++nt) {
        f32x4 sa = {};
        sa = __builtin_amdgcn_mfma_f32_16x16x32_bf16(kf[nt * 2 + 0], qf[x][0], sa, 0, 0, 0);
        sa = __builtin_amdgcn_mfma_f32_16x16x32_bf16(kf[nt * 2 + 1], qf[x][1], sa, 0, 0, 0);
        sv[nt] = sa;
      }
      __builtin_amdgcn_s_setprio(0);

      const int qrx = qrow + 16 * x;      // subtile's first row (16-aligned)
      float mt = -__builtin_inff();
      if (kv0 + 63 > qrx) {               // tile reaches/passes the diagonal
        const int qi = qrx + fr;
#pragma unroll
        for (int nt = 0; nt < 4; ++nt)
#pragma unroll
          for (int r = 0; r < 4; ++r) {
            int kvi = kv0 + 32 * (nt >> 1) + 8 * fq + 4 * (nt & 1) + r;
            float v = sv[nt][r];
            if (kvi > qi) v = -__builtin_inff();
            sv[nt][r] = v;
            mt = fmaxf(mt, v);
          }
      } else {                            // strictly below diagonal: unmasked
#pragma unroll
        for (int nt = 0; nt < 4; ++nt)
          mt = fmaxf(mt, fmaxf(fmaxf(sv[nt][0], sv[nt][1]),
                               fmaxf(sv[nt][2], sv[nt][3])));
      }
      mt = fmaxf(mt, __shfl_xor(mt, 16));
      mt = fmaxf(mt, __shfl_xor(mt, 32));

      // defer-max: rescale only when the row max grew by > 8 log2-units
      if (__any(mt > m_run[x] + 8.0f)) {
        float mn = fmaxf(m_run[x], mt);   // per-lane: mn==m_run -> c=exp2(0)=1
        float c  = exp2fast(m_run[x] - mn);   // first tile: exp2(-inf)=0
        m_run[x] = mn;
#pragma unroll
        for (int dt = 0; dt < 4; ++dt) acc[x][dt] *= c;
        l_run[x] *= c;
      }

      float lsum = 0.f;
      int pw[8];                          // dwords: pw[(nt>>1)*4 + (nt&1)*2 + w]
#pragma unroll
      for (int nt = 0; nt < 4; ++nt) {
        float p0 = exp2fast(sv[nt][0] - m_run[x]);   // masked -> 0
        float p1 = exp2fast(sv[nt][1] - m_run[x]);
        float p2 = exp2fast(sv[nt][2] - m_run[x]);
        float p3 = exp2fast(sv[nt][3] - m_run[x]);
        lsum += (p0 + p1) + (p2 + p3);
        pw[(nt >> 1) * 4 + (nt & 1) * 2 + 0] = (int)cvt_pk_bf16(p0, p1);
        pw[(nt >> 1) * 4 + (nt & 1) * 2 + 1] = (int)cvt_pk_bf16(p2, p3);
      }
      l_run[x] += lsum;                   // lane-partial (reduced at finalize)

#pragma unroll
      for (int t = 0; t < 2; ++t) {
        int4 v4 = {pw[t * 4 + 0], pw[t * 4 + 1], pw[t * 4 + 2], pw[t * 4 + 3]};
        pf[x][t] = __builtin_bit_cast(bf16x8, v4);
      }
    }

    // ---- O^T += V^T P^T : P straight from registers ----
    __builtin_amdgcn_s_setprio(1);
#pragma unroll
    for (int t = 0; t < 2; ++t)
#pragma unroll
      for (int dt = 0; dt < 4; ++dt) {
        bf16x8 vf = *(const bf16x8*)&VTs[cur][dt * 16 + fr][t * 32 + fq * 8];
        acc[0][dt] = __builtin_amdgcn_mfma_f32_16x16x32_bf16(vf, pf[0][t], acc[0][dt], 0, 0, 0);
        acc[1][dt] = __builtin_amdgcn_mfma_f32_16x16x32_bf16(vf, pf[1][t], acc[1][dt], 0, 0, 0);
      }
    __builtin_amdgcn_s_setprio(0);

    if (have_next) stage_write(cur ^ 1);          // next tile -> other buffer
    kv0 += 64;
  }

  // ---- finalize both subtiles ----
#pragma unroll
  for (int x = 0; x < 2; ++x) {
    float l = l_run[x];
    l += __shfl_xor(l, 16);               // cross-fq reduce
    l += __shfl_xor(l, 32);
    float linv = 1.0f / l;
    unsigned short* orow =
        ctx + (size_t)(b * T_ + qrow + 16 * x + fr) * C_ + h * D_;
#pragma unroll
    for (int dt = 0; dt < 4; ++dt) {
      u16x4 o;
#pragma unroll
      for (int r = 0; r < 4; ++r) o[r] = f2bf(acc[x][dt][r] * linv);
      *(u16x4*)&orow[dt * 16 + fq * 4] = o;
    }
  }
}

// ---------------------------------------------------------------------------
extern "C" void kernel_launch(void* const* d_in, const int* in_sizes, int n_in,
                              void* d_out, int out_size, void* d_ws, size_t ws_size,
                              hipStream_t stream) {
  const float* x  = (const float*)d_in[0];
  // d_in[1] = mask: exactly tril -> causality hardcoded in attn kernel
  const float* Wq = (const float*)d_in[2];
  const float* Wk = (const float*)d_in[3];
  const float* Wv = (const float*)d_in[4];
  const float* Wo = (const float*)d_in[5];
  const float* bo = (const float*)d_in[6];

  // workspace carve (all bf16/ushort elements)
  unsigned short* xb  = (unsigned short*)d_ws;     // 8192*1024
  unsigned short* wqt = xb  + (size_t)M_ * C_;     // [3072][1024] fused QKV W^T
  unsigned short* wot = wqt + (size_t)3 * C_ * C_;
  unsigned short* Qb  = wot + (size_t)C_ * C_;     // (B,H,T,D), then K, then V
  unsigned short* ctxb = xb;                       // alias: x dead after QKV

  conv_x_kernel<<<4096, 256, 0, stream>>>(x, xb);
  conv_wt_kernel<<<dim3(16, 16, 4), 256, 0, stream>>>(Wq, Wk, Wv, Wo, wqt);

  gemm128<0><<<dim3(24, M_ / 128), 256, 0, stream>>>(xb, wqt, Qb, nullptr, C_);

  attn_kernel<<<dim3(512), 512, 0, stream>>>(
      Qb, Qb + (size_t)M_ * C_, Qb + (size_t)2 * M_ * C_, ctxb);

  gemm128<1><<<dim3(8, M_ / 128), 256, 0, stream>>>(ctxb, wot, d_out, bo, C_);
}

// Round 19
// 178.391 us; speedup vs baseline: 1.0266x; 1.0266x over previous
//
#include <hip/hip_runtime.h>
#include <hip/hip_bf16.h>

// ---------------------------------------------------------------------------
// MultiHeadAttention: x(B,T,C) fp32 -> out(B,T,C) fp32
// B=4 T=2048 C=1024 H=16 D=64. Internally bf16 MFMA with fp32 accumulation.
// Pipeline: convert -> fused QKV GEMM -> pipelined causal flash attn -> out GEMM.
// ---------------------------------------------------------------------------

#define B_  4
#define T_  2048
#define C_  1024
#define H_  16
#define D_  64
#define M_  (B_*T_)   // 8192 rows for the projection GEMMs

#define LOG2E 1.4426950408889634f

using bf16x8 = __attribute__((ext_vector_type(8))) short;
using f32x4  = __attribute__((ext_vector_type(4))) float;
using u16x4  = __attribute__((ext_vector_type(4))) unsigned short;

__device__ __forceinline__ unsigned short f2bf(float f) {
  union { float f; unsigned u; } cv; cv.f = f;
  unsigned u = cv.u;
  u += 0x7fffu + ((u >> 16) & 1u);   // RNE (inputs are finite)
  return (unsigned short)(u >> 16);
}

// pack two f32 -> one dword of 2 bf16 (RNE), single VALU op
__device__ __forceinline__ unsigned cvt_pk_bf16(float lo, float hi) {
  unsigned r;
  asm("v_cvt_pk_bf16_f32 %0, %1, %2" : "=v"(r) : "v"(lo), "v"(hi));
  return r;
}

__device__ __forceinline__ float exp2fast(float x) {
#if __has_builtin(__builtin_amdgcn_exp2f)
  return __builtin_amdgcn_exp2f(x);
#else
  return exp2f(x);
#endif
}

__device__ __forceinline__ void lds_load16(void* lds, const void* g) {
  __builtin_amdgcn_global_load_lds(
      (const __attribute__((address_space(1))) unsigned int*)g,
      (__attribute__((address_space(3))) unsigned int*)lds,
      16, 0, 0);
}

// ---------------------------------------------------------------------------
// Kernel 1: x fp32 -> bf16 (8 elems/thread, vectorized)
// ---------------------------------------------------------------------------
__global__ __launch_bounds__(256) void conv_x_kernel(
    const float* __restrict__ x, unsigned short* __restrict__ xb) {
  int i = blockIdx.x * 256 + threadIdx.x;      // group of 8 elements
  const float4* xv = (const float4*)x;
  float4 a = xv[i * 2 + 0];
  float4 b = xv[i * 2 + 1];
  using u16x8 = __attribute__((ext_vector_type(8))) unsigned short;
  u16x8 o;
  o[0]=f2bf(a.x); o[1]=f2bf(a.y); o[2]=f2bf(a.z); o[3]=f2bf(a.w);
  o[4]=f2bf(b.x); o[5]=f2bf(b.y); o[6]=f2bf(b.z); o[7]=f2bf(b.w);
  *(u16x8*)&xb[(size_t)i * 8] = o;
}

// ---------------------------------------------------------------------------
// Kernel 2: 4 weights (K x N fp32, applied as x@W) -> W^T (N x K bf16), batched
// ---------------------------------------------------------------------------
__global__ __launch_bounds__(256) void conv_wt_kernel(
    const float* __restrict__ W0, const float* __restrict__ W1,
    const float* __restrict__ W2, const float* __restrict__ W3,
    unsigned short* __restrict__ WT) {
  __shared__ float tile[64][65];
  const float* W = (blockIdx.z == 0) ? W0 : (blockIdx.z == 1) ? W1
                 : (blockIdx.z == 2) ? W2 : W3;
  unsigned short* o = WT + (size_t)blockIdx.z * C_ * C_;
  const int k0 = blockIdx.y * 64, n0 = blockIdx.x * 64;
  const int tr = threadIdx.x >> 6;   // 0..3
  const int tc = threadIdx.x & 63;   // 0..63
#pragma unroll
  for (int i = 0; i < 16; ++i) {
    int k = tr + i * 4;
    tile[k][tc] = W[(size_t)(k0 + k) * C_ + n0 + tc];
  }
  __syncthreads();
#pragma unroll
  for (int i = 0; i < 16; ++i) {
    int n = tr + i * 4;
    o[(size_t)(n0 + n) * C_ + k0 + tc] = f2bf(tile[tc][n]);
  }
}

// ---------------------------------------------------------------------------
// Kernel 3: GEMM  C[M x N] = A[M x K] * BT[N x K]^T
// 128x128 tile, BK=32, 4 waves (2x2 of 64x64), global_load_lds staging.
// XCD-aware block swizzle (R13-proven): bid -> xcd=bid&7; bm=xcd+8*(i&7),
// bn=i>>3.
// EPI 0 (QKV): R17-EXACT unswapped mfma + scalar b16 epilogue (R18's swap
//   regressed QKV 79->84 us; reverted).
// EPI 1 (out): operands SWAPPED (acc = mfma(bfr, af, acc)) -> lane holds
//   C[m=...+fr][n=...+fq*4+r], 4 consecutive n -> one float4 store + one
//   float4 bias load per fragment (16x16B vs 64x4B).
// ---------------------------------------------------------------------------
template <int EPI>
__global__ __launch_bounds__(256) void gemm128(
    const unsigned short* __restrict__ A, const unsigned short* __restrict__ BT,
    void* __restrict__ out, const float* __restrict__ bias, int K) {
  __shared__ unsigned short As[128][32];   // 8 KB
  __shared__ unsigned short Bs[128][32];   // 8 KB

  const int tid  = threadIdx.x;
  const int wid  = tid >> 6, lane = tid & 63;
  const int wr   = wid >> 1, wc = wid & 1;
  const int fr   = lane & 15, fq = lane >> 4;
  const int bid  = blockIdx.y * gridDim.x + blockIdx.x;   // dispatch-linear
  const int xcd  = bid & 7, ii = bid >> 3;
  const int bm   = xcd + 8 * (ii & 7);     // 0..63
  const int bn   = ii >> 3;                // 0..gridDim.x-1

  const unsigned short* aP = A  + (size_t)(bm * 128 + wid * 32 + (lane >> 2)) * K + (lane & 3) * 8;
  const unsigned short* bP = BT + (size_t)(bn * 128 + wid * 32 + (lane >> 2)) * K + (lane & 3) * 8;
  unsigned short* asB = &As[wid * 32][0];
  unsigned short* bsB = &Bs[wid * 32][0];

  f32x4 acc[4][4] = {};

  for (int k0 = 0; k0 < K; k0 += 32) {
    lds_load16(asB,           aP + k0);
    lds_load16(asB + 16 * 32, aP + (size_t)16 * K + k0);
    lds_load16(bsB,           bP + k0);
    lds_load16(bsB + 16 * 32, bP + (size_t)16 * K + k0);
    __syncthreads();

    bf16x8 af[4], bfr[4];
#pragma unroll
    for (int mi = 0; mi < 4; ++mi)
      af[mi] = *(const bf16x8*)&As[wr * 64 + mi * 16 + fr][fq * 8];
#pragma unroll
    for (int ni = 0; ni < 4; ++ni)
      bfr[ni] = *(const bf16x8*)&Bs[wc * 64 + ni * 16 + fr][fq * 8];
#pragma unroll
    for (int mi = 0; mi < 4; ++mi)
#pragma unroll
      for (int ni = 0; ni < 4; ++ni) {
        if (EPI == 0)
          acc[mi][ni] = __builtin_amdgcn_mfma_f32_16x16x32_bf16(
              af[mi], bfr[ni], acc[mi][ni], 0, 0, 0);       // C layout
        else
          acc[mi][ni] = __builtin_amdgcn_mfma_f32_16x16x32_bf16(
              bfr[ni], af[mi], acc[mi][ni], 0, 0, 0);       // C^T layout
      }
    __syncthreads();
  }

  if (EPI == 0) {
    // fused QKV (R17-exact): n in [0,3072) -> matrix (Q/K/V), head, d.
    // Q scaled by log2(e)/sqrt(D) -> attention exponentials become exp2.
    unsigned short* o = (unsigned short*)out;
#pragma unroll
    for (int mi = 0; mi < 4; ++mi) {
      int m  = bm * 128 + wr * 64 + mi * 16 + fq * 4;
      int b  = m >> 11;          // T=2048
      int t0 = m & 2047;
#pragma unroll
      for (int ni = 0; ni < 4; ++ni) {
        int n = bn * 128 + wc * 64 + ni * 16 + fr;
        int mat = n >> 10;
        int nc  = n & 1023;
        int h = nc >> 6, d = nc & 63;
        float sc_ = (mat == 0) ? (0.125f * LOG2E) : 1.0f;
        size_t base = (size_t)mat * ((size_t)M_ * C_) + ((size_t)(b * H_ + h) << 17) + d;
#pragma unroll
        for (int r = 0; r < 4; ++r)
          o[base + (size_t)(t0 + r) * D_] = f2bf(acc[mi][ni][r] * sc_);
      }
    }
  } else {
    // out-projection: lane holds 4 consecutive n -> float4 store + bias.
    float* o = (float*)out;
#pragma unroll
    for (int mi = 0; mi < 4; ++mi) {
      int m = bm * 128 + wr * 64 + mi * 16 + fr;
#pragma unroll
      for (int ni = 0; ni < 4; ++ni) {
        int n0 = bn * 128 + wc * 64 + ni * 16 + fq * 4;
        float4 bv = *(const float4*)&bias[n0];
        float4 ov;
        ov.x = acc[mi][ni][0] + bv.x;
        ov.y = acc[mi][ni][1] + bv.y;
        ov.z = acc[mi][ni][2] + bv.z;
        ov.w = acc[mi][ni][3] + bv.w;
        *(float4*)&o[(size_t)m * C_ + n0] = ov;
      }
    }
  }
}

// ---------------------------------------------------------------------------
// Kernel 4: pipelined causal flash attention, 8 WAVES (512 thr), QBLK=256,
// KVBLK=64, no P-LDS. (R17-proven, unchanged.)
// K/V double-buffered, ONE barrier/step, stage-to-regs right after the
// barrier, LDS-write after compute into buf[cur^1]; defer-max rescale;
// K rows staged PERMUTED (row l(g) = g5 g2 g4g3 g1g0) so packed P dwords
// are exactly the PV B-fragments (P never touches LDS); lane-partial l;
// staging role-split (waves 0-3 stage V, waves 4-7 stage K); no skips.
// Grid 512, LPT (qt=7-(j>>3)), head-per-XCD swizzle.
// ---------------------------------------------------------------------------
#define KSTR 72
__global__ __launch_bounds__(512) void attn_kernel(
    const unsigned short* __restrict__ Qg, const unsigned short* __restrict__ Kg,
    const unsigned short* __restrict__ Vg, unsigned short* __restrict__ ctx) {
  __shared__ __align__(16) unsigned short Ks[2][64][KSTR];    // [buf][kv'][d]
  __shared__ __align__(16) unsigned short VTs[2][64][KSTR];   // [buf][d][kv]

  const int tid = threadIdx.x, wid = tid >> 6, lane = tid & 63;
  const int fr = lane & 15, fq = lane >> 4;

  const int bid = blockIdx.x;
  const int xcd = bid & 7, j = bid >> 3;        // j in 0..63
  const int bh = xcd * 8 + (j & 7);             // 8 heads per XCD (L2 locality)
  const int qt = 7 - (j >> 3);                  // q-tile 0..7, longest first
  const int b = bh >> 4, h = bh & 15;
  const size_t base = (size_t)bh * (T_ * D_);

  // Staging roles: waves 0-3 (tid<256) stage V; waves 4-7 stage K.
  const int vc = (tid & 255) >> 5, vr_ = tid & 31;
  const int kt = tid & 255, ksr = kt >> 2, ksc = kt & 3;
  const int kpr = ((ksr >> 5) & 1) * 32 + ((ksr >> 2) & 1) * 16 +
                  ((ksr >> 3) & 3) * 4 + (ksr & 3);
  const unsigned short* Kptr = Kg + base + (size_t)ksr * D_ + ksc * 8;
  const unsigned short* Vptr = Vg + base + (size_t)(2 * vr_) * D_ + vc * 8;

  int4 sa_, sb_;    // staging payload (role-dependent)
  auto stage_load = [&](int kv) {
    if (wid < 4) {  // V role
      const unsigned short* vp = Vptr + (size_t)kv * D_;
      sa_ = *(const int4*)vp;          // kv row 2vr_
      sb_ = *(const int4*)(vp + D_);   // kv row 2vr_+1
    } else {        // K role
      const unsigned short* kp = Kptr + (size_t)kv * D_;
      sa_ = *(const int4*)kp;
      sb_ = *(const int4*)(kp + 32);
    }
  };
  auto stage_write = [&](int nb) {
    if (wid < 4) {  // V: packed kv-pair transpose writes
      const unsigned short* pa = (const unsigned short*)&sa_;
      const unsigned short* pb = (const unsigned short*)&sb_;
#pragma unroll
      for (int i = 0; i < 8; ++i) {
        unsigned w = (unsigned)pa[i] | ((unsigned)pb[i] << 16);
        *(unsigned*)&VTs[nb][vc * 8 + i][2 * vr_] = w;
      }
    } else {        // K: permuted-row b128 writes
      *(int4*)&Ks[nb][kpr][ksc * 8]       = sa_;
      *(int4*)&Ks[nb][kpr][(ksc + 4) * 8] = sb_;
    }
  };

  stage_load(0);
  stage_write(0);           // tile 0 -> buf 0 (visible after first barrier)

  const int qbase = qt * 256;
  const int qrow = qbase + wid * 32;    // wave's first q row

  bf16x8 qf[2][2];          // [subtile][t]
#pragma unroll
  for (int x = 0; x < 2; ++x)
#pragma unroll
    for (int t = 0; t < 2; ++t)
      qf[x][t] = *(const bf16x8*)
          &Qg[base + (size_t)(qrow + 16 * x + fr) * D_ + t * 32 + fq * 8];

  f32x4 acc[2][4] = {};     // [subtile][d-tile]; O^T: q=row+fr, d=dt*16+fq*4+r
  float m_run[2] = {-__builtin_inff(), -__builtin_inff()};
  float l_run[2] = {0.f, 0.f};   // lane-partial; cross-fq reduced at finalize

  const int nsteps = 4 * qt + 4;   // kv tiles of 64: 0 .. qbase+192
  int kv0 = 0;
  for (int s = 0; s < nsteps; ++s) {
    const int  cur = s & 1;
    const bool have_next = (s + 1 < nsteps);

    __syncthreads();                              // buf[cur] ready; buf[cur^1] free
    if (have_next) stage_load(kv0 + 64);          // prefetch to regs (T14)

    // ---- K fragments (shared by both subtiles; data permuted at staging) ----
    bf16x8 kf[8];
#pragma unroll
    for (int nt = 0; nt < 4; ++nt)
#pragma unroll
      for (int t = 0; t < 2; ++t)
        kf[nt * 2 + t] = *(const bf16x8*)&Ks[cur][nt * 16 + fr][t * 32 + fq * 8];

    // ---- per-subtile: S^T = K Q^T, softmax, P packed in registers ----
    bf16x8 pf[2][2];        // [subtile][t] PV B-fragments, lane-local
#pragma unroll
    for (int x = 0; x < 2; ++x) {
      f32x4 sv[4];
      __builtin_amdgcn_s_setprio(1);
#pragma unroll
      for (int nt = 0; nt < 4; ++nt) {
        f32x4 sa = {};
        sa = __builtin_amdgcn_mfma_f32_16x16x32_bf16(kf[nt * 2 + 0], qf[x][0], sa, 0, 0, 0);
        sa = __builtin_amdgcn_mfma_f32_16x16x32_bf16(kf[nt * 2 + 1], qf[x][1], sa, 0, 0, 0);
        sv[nt] = sa;
      }
      __builtin_amdgcn_s_setprio(0);

      const int qrx = qrow + 16 * x;      // subtile's first row (16-aligned)
      float mt = -__builtin_inff();
      if (kv0 + 63 > qrx) {               // tile reaches/passes the diagonal
        const int qi = qrx + fr;
#pragma unroll
        for (int nt = 0; nt < 4; ++nt)
#pragma unroll
          for (int r = 0; r < 4; ++r) {
            int kvi = kv0 + 32 * (nt >> 1) + 8 * fq + 4 * (nt & 1) + r;
            float v = sv[nt][r];
            if (kvi > qi) v = -__builtin_inff();
            sv[nt][r] = v;
            mt = fmaxf(mt, v);
          }
      } else {                            // strictly below diagonal: unmasked
#pragma unroll
        for (int nt = 0; nt < 4; ++nt)
          mt = fmaxf(mt, fmaxf(fmaxf(sv[nt][0], sv[nt][1]),
                               fmaxf(sv[nt][2], sv[nt][3])));
      }
      mt = fmaxf(mt, __shfl_xor(mt, 16));
      mt = fmaxf(mt, __shfl_xor(mt, 32));

      // defer-max: rescale only when the row max grew by > 8 log2-units
      if (__any(mt > m_run[x] + 8.0f)) {
        float mn = fmaxf(m_run[x], mt);   // per-lane: mn==m_run -> c=exp2(0)=1
        float c  = exp2fast(m_run[x] - mn);   // first tile: exp2(-inf)=0
        m_run[x] = mn;
#pragma unroll
        for (int dt = 0; dt < 4; ++dt) acc[x][dt] *= c;
        l_run[x] *= c;
      }

      float lsum = 0.f;
      int pw[8];                          // dwords: pw[(nt>>1)*4 + (nt&1)*2 + w]
#pragma unroll
      for (int nt = 0; nt < 4; ++nt) {
        float p0 = exp2fast(sv[nt][0] - m_run[x]);   // masked -> 0
        float p1 = exp2fast(sv[nt][1] - m_run[x]);
        float p2 = exp2fast(sv[nt][2] - m_run[x]);
        float p3 = exp2fast(sv[nt][3] - m_run[x]);
        lsum += (p0 + p1) + (p2 + p3);
        pw[(nt >> 1) * 4 + (nt & 1) * 2 + 0] = (int)cvt_pk_bf16(p0, p1);
        pw[(nt >> 1) * 4 + (nt & 1) * 2 + 1] = (int)cvt_pk_bf16(p2, p3);
      }
      l_run[x] += lsum;                   // lane-partial (reduced at finalize)

#pragma unroll
      for (int t = 0; t < 2; ++t) {
        int4 v4 = {pw[t * 4 + 0], pw[t * 4 + 1], pw[t * 4 + 2], pw[t * 4 + 3]};
        pf[x][t] = __builtin_bit_cast(bf16x8, v4);
      }
    }

    // ---- O^T += V^T P^T : P straight from registers ----
    __builtin_amdgcn_s_setprio(1);
#pragma unroll
    for (int t = 0; t < 2; ++t)
#pragma unroll
      for (int dt = 0; dt < 4; ++dt) {
        bf16x8 vf = *(const bf16x8*)&VTs[cur][dt * 16 + fr][t * 32 + fq * 8];
        acc[0][dt] = __builtin_amdgcn_mfma_f32_16x16x32_bf16(vf, pf[0][t], acc[0][dt], 0, 0, 0);
        acc[1][dt] = __builtin_amdgcn_mfma_f32_16x16x32_bf16(vf, pf[1][t], acc[1][dt], 0, 0, 0);
      }
    __builtin_amdgcn_s_setprio(0);

    if (have_next) stage_write(cur ^ 1);          // next tile -> other buffer
    kv0 += 64;
  }

  // ---- finalize both subtiles ----
#pragma unroll
  for (int x = 0; x < 2; ++x) {
    float l = l_run[x];
    l += __shfl_xor(l, 16);               // cross-fq reduce
    l += __shfl_xor(l, 32);
    float linv = 1.0f / l;
    unsigned short* orow =
        ctx + (size_t)(b * T_ + qrow + 16 * x + fr) * C_ + h * D_;
#pragma unroll
    for (int dt = 0; dt < 4; ++dt) {
      u16x4 o;
#pragma unroll
      for (int r = 0; r < 4; ++r) o[r] = f2bf(acc[x][dt][r] * linv);
      *(u16x4*)&orow[dt * 16 + fq * 4] = o;
    }
  }
}

// ---------------------------------------------------------------------------
extern "C" void kernel_launch(void* const* d_in, const int* in_sizes, int n_in,
                              void* d_out, int out_size, void* d_ws, size_t ws_size,
                              hipStream_t stream) {
  const float* x  = (const float*)d_in[0];
  // d_in[1] = mask: exactly tril -> causality hardcoded in attn kernel
  const float* Wq = (const float*)d_in[2];
  const float* Wk = (const float*)d_in[3];
  const float* Wv = (const float*)d_in[4];
  const float* Wo = (const float*)d_in[5];
  const float* bo = (const float*)d_in[6];

  // workspace carve (all bf16/ushort elements)
  unsigned short* xb  = (unsigned short*)d_ws;     // 8192*1024
  unsigned short* wqt = xb  + (size_t)M_ * C_;     // [3072][1024] fused QKV W^T
  unsigned short* wot = wqt + (size_t)3 * C_ * C_;
  unsigned short* Qb  = wot + (size_t)C_ * C_;     // (B,H,T,D), then K, then V
  unsigned short* ctxb = xb;                       // alias: x dead after QKV

  conv_x_kernel<<<4096, 256, 0, stream>>>(x, xb);
  conv_wt_kernel<<<dim3(16, 16, 4), 256, 0, stream>>>(Wq, Wk, Wv, Wo, wqt);

  gemm128<0><<<dim3(24, M_ / 128), 256, 0, stream>>>(xb, wqt, Qb, nullptr, C_);

  attn_kernel<<<dim3(512), 512, 0, stream>>>(
      Qb, Qb + (size_t)M_ * C_, Qb + (size_t)2 * M_ * C_, ctxb);

  gemm128<1><<<dim3(8, M_ / 128), 256, 0, stream>>>(ctxb, wot, d_out, bo, C_);
}

// Round 20
// 164.258 us; speedup vs baseline: 1.1150x; 1.0860x over previous
//
#include <hip/hip_runtime.h>
#include <hip/hip_bf16.h>

// ---------------------------------------------------------------------------
// MultiHeadAttention: x(B,T,C) fp32 -> out(B,T,C) fp32
// B=4 T=2048 C=1024 H=16 D=64. Internally bf16 MFMA with fp32 accumulation.
// Pipeline: convert -> fused QKV GEMM -> pipelined causal flash attn -> out GEMM.
// ---------------------------------------------------------------------------

#define B_  4
#define T_  2048
#define C_  1024
#define H_  16
#define D_  64
#define M_  (B_*T_)   // 8192 rows for the projection GEMMs

#define LOG2E 1.4426950408889634f

using bf16x8 = __attribute__((ext_vector_type(8))) short;
using f32x4  = __attribute__((ext_vector_type(4))) float;
using u16x4  = __attribute__((ext_vector_type(4))) unsigned short;

__device__ __forceinline__ unsigned short f2bf(float f) {
  union { float f; unsigned u; } cv; cv.f = f;
  unsigned u = cv.u;
  u += 0x7fffu + ((u >> 16) & 1u);   // RNE (inputs are finite)
  return (unsigned short)(u >> 16);
}

// pack two f32 -> one dword of 2 bf16 (RNE), single VALU op
__device__ __forceinline__ unsigned cvt_pk_bf16(float lo, float hi) {
  unsigned r;
  asm("v_cvt_pk_bf16_f32 %0, %1, %2" : "=v"(r) : "v"(lo), "v"(hi));
  return r;
}

__device__ __forceinline__ float exp2fast(float x) {
#if __has_builtin(__builtin_amdgcn_exp2f)
  return __builtin_amdgcn_exp2f(x);
#else
  return exp2f(x);
#endif
}

__device__ __forceinline__ void lds_load16(void* lds, const void* g) {
  __builtin_amdgcn_global_load_lds(
      (const __attribute__((address_space(1))) unsigned int*)g,
      (__attribute__((address_space(3))) unsigned int*)lds,
      16, 0, 0);
}

// ---------------------------------------------------------------------------
// Kernel 1: x fp32 -> bf16 (8 elems/thread, vectorized)
// ---------------------------------------------------------------------------
__global__ __launch_bounds__(256) void conv_x_kernel(
    const float* __restrict__ x, unsigned short* __restrict__ xb) {
  int i = blockIdx.x * 256 + threadIdx.x;      // group of 8 elements
  const float4* xv = (const float4*)x;
  float4 a = xv[i * 2 + 0];
  float4 b = xv[i * 2 + 1];
  using u16x8 = __attribute__((ext_vector_type(8))) unsigned short;
  u16x8 o;
  o[0]=f2bf(a.x); o[1]=f2bf(a.y); o[2]=f2bf(a.z); o[3]=f2bf(a.w);
  o[4]=f2bf(b.x); o[5]=f2bf(b.y); o[6]=f2bf(b.z); o[7]=f2bf(b.w);
  *(u16x8*)&xb[(size_t)i * 8] = o;
}

// ---------------------------------------------------------------------------
// Kernel 2: 4 weights (K x N fp32, applied as x@W) -> W^T (N x K bf16), batched
// ---------------------------------------------------------------------------
__global__ __launch_bounds__(256) void conv_wt_kernel(
    const float* __restrict__ W0, const float* __restrict__ W1,
    const float* __restrict__ W2, const float* __restrict__ W3,
    unsigned short* __restrict__ WT) {
  __shared__ float tile[64][65];
  const float* W = (blockIdx.z == 0) ? W0 : (blockIdx.z == 1) ? W1
                 : (blockIdx.z == 2) ? W2 : W3;
  unsigned short* o = WT + (size_t)blockIdx.z * C_ * C_;
  const int k0 = blockIdx.y * 64, n0 = blockIdx.x * 64;
  const int tr = threadIdx.x >> 6;   // 0..3
  const int tc = threadIdx.x & 63;   // 0..63
#pragma unroll
  for (int i = 0; i < 16; ++i) {
    int k = tr + i * 4;
    tile[k][tc] = W[(size_t)(k0 + k) * C_ + n0 + tc];
  }
  __syncthreads();
#pragma unroll
  for (int i = 0; i < 16; ++i) {
    int n = tr + i * 4;
    o[(size_t)(n0 + n) * C_ + k0 + tc] = f2bf(tile[tc][n]);
  }
}

// ---------------------------------------------------------------------------
// Kernel 3: GEMM  C[M x N] = A[M x K] * BT[N x K]^T
// 128x128 tile, BK=64, 4 waves (2x2 of 64x64), global_load_lds staging with
// BOTH-SIDES XOR SWIZZLE (T2 + rule #21): LDS [128][64] rows are 128B
// (32-way conflict if linear), so logical 16B-chunk j of row r is stored at
// chunk j ^ (r&7). gload_lds dest stays LINEAR (1KB = 8 rows); the per-lane
// GLOBAL source absorbs the permutation: src chunk = (lane&7) ^ (lane>>3)
// (8-row chunk base is 8-aligned => r&7 == lane>>3). Fragment reads use
// chunk (fq+4t) ^ (fr&7) -> banks 4*((fq+4t)^(r&7)): 8 distinct, 2 lanes
// each = conflict-free. Half the barriers of BK=32 (16 iters).
// XCD-aware block swizzle (R13-proven). EPI 0 (QKV): R17-exact epilogue,
// unswapped MFMA. EPI 1 (out): swapped MFMA -> float4 stores + bias.
// ---------------------------------------------------------------------------
template <int EPI>
__global__ __launch_bounds__(256) void gemm128(
    const unsigned short* __restrict__ A, const unsigned short* __restrict__ BT,
    void* __restrict__ out, const float* __restrict__ bias, int K) {
  __shared__ unsigned short As[128][64];   // 16 KB
  __shared__ unsigned short Bs[128][64];   // 16 KB

  const int tid  = threadIdx.x;
  const int wid  = tid >> 6, lane = tid & 63;
  const int wr   = wid >> 1, wc = wid & 1;
  const int fr   = lane & 15, fq = lane >> 4;
  const int bid  = blockIdx.y * gridDim.x + blockIdx.x;   // dispatch-linear
  const int xcd  = bid & 7, ii = bid >> 3;
  const int bm   = xcd + 8 * (ii & 7);     // 0..63
  const int bn   = ii >> 3;                // 0..gridDim.x-1

  // staging: wave wid covers rows [wid*32, wid*32+32) as 4 chunks of 8 rows;
  // lane -> row offset lane>>3, source 16B-chunk (lane&7)^(lane>>3)
  const int srow = lane >> 3;
  const int schk = (lane & 7) ^ (lane >> 3);
  const unsigned short* aP =
      A  + (size_t)(bm * 128 + wid * 32 + srow) * K + schk * 8;
  const unsigned short* bP =
      BT + (size_t)(bn * 128 + wid * 32 + srow) * K + schk * 8;

  // fragment read chunks (swizzled): chunk(t) = (fq + 4t) ^ (fr & 7)
  const int rc0 = (fq + 0) ^ (fr & 7);
  const int rc1 = (fq + 4) ^ (fr & 7);

  f32x4 acc[4][4] = {};

  for (int k0 = 0; k0 < K; k0 += 64) {
#pragma unroll
    for (int c = 0; c < 4; ++c)
      lds_load16(&As[wid * 32 + c * 8][0], aP + (size_t)(c * 8) * K + k0);
#pragma unroll
    for (int c = 0; c < 4; ++c)
      lds_load16(&Bs[wid * 32 + c * 8][0], bP + (size_t)(c * 8) * K + k0);
    __syncthreads();

    bf16x8 af[4][2], bfr[4][2];
#pragma unroll
    for (int mi = 0; mi < 4; ++mi) {
      const unsigned short* rowp = &As[wr * 64 + mi * 16 + fr][0];
      af[mi][0] = *(const bf16x8*)(rowp + rc0 * 8);
      af[mi][1] = *(const bf16x8*)(rowp + rc1 * 8);
    }
#pragma unroll
    for (int ni = 0; ni < 4; ++ni) {
      const unsigned short* rowp = &Bs[wc * 64 + ni * 16 + fr][0];
      bfr[ni][0] = *(const bf16x8*)(rowp + rc0 * 8);
      bfr[ni][1] = *(const bf16x8*)(rowp + rc1 * 8);
    }
#pragma unroll
    for (int mi = 0; mi < 4; ++mi)
#pragma unroll
      for (int ni = 0; ni < 4; ++ni) {
        if (EPI == 0) {
          acc[mi][ni] = __builtin_amdgcn_mfma_f32_16x16x32_bf16(
              af[mi][0], bfr[ni][0], acc[mi][ni], 0, 0, 0);
          acc[mi][ni] = __builtin_amdgcn_mfma_f32_16x16x32_bf16(
              af[mi][1], bfr[ni][1], acc[mi][ni], 0, 0, 0);
        } else {
          acc[mi][ni] = __builtin_amdgcn_mfma_f32_16x16x32_bf16(
              bfr[ni][0], af[mi][0], acc[mi][ni], 0, 0, 0);
          acc[mi][ni] = __builtin_amdgcn_mfma_f32_16x16x32_bf16(
              bfr[ni][1], af[mi][1], acc[mi][ni], 0, 0, 0);
        }
      }
    __syncthreads();
  }

  if (EPI == 0) {
    // fused QKV (R17-exact): n in [0,3072) -> matrix (Q/K/V), head, d.
    // Q scaled by log2(e)/sqrt(D) -> attention exponentials become exp2.
    unsigned short* o = (unsigned short*)out;
#pragma unroll
    for (int mi = 0; mi < 4; ++mi) {
      int m  = bm * 128 + wr * 64 + mi * 16 + fq * 4;
      int b  = m >> 11;          // T=2048
      int t0 = m & 2047;
#pragma unroll
      for (int ni = 0; ni < 4; ++ni) {
        int n = bn * 128 + wc * 64 + ni * 16 + fr;
        int mat = n >> 10;
        int nc  = n & 1023;
        int h = nc >> 6, d = nc & 63;
        float sc_ = (mat == 0) ? (0.125f * LOG2E) : 1.0f;
        size_t base = (size_t)mat * ((size_t)M_ * C_) + ((size_t)(b * H_ + h) << 17) + d;
#pragma unroll
        for (int r = 0; r < 4; ++r)
          o[base + (size_t)(t0 + r) * D_] = f2bf(acc[mi][ni][r] * sc_);
      }
    }
  } else {
    // out-projection: lane holds 4 consecutive n -> float4 store + bias.
    float* o = (float*)out;
#pragma unroll
    for (int mi = 0; mi < 4; ++mi) {
      int m = bm * 128 + wr * 64 + mi * 16 + fr;
#pragma unroll
      for (int ni = 0; ni < 4; ++ni) {
        int n0 = bn * 128 + wc * 64 + ni * 16 + fq * 4;
        float4 bv = *(const float4*)&bias[n0];
        float4 ov;
        ov.x = acc[mi][ni][0] + bv.x;
        ov.y = acc[mi][ni][1] + bv.y;
        ov.z = acc[mi][ni][2] + bv.z;
        ov.w = acc[mi][ni][3] + bv.w;
        *(float4*)&o[(size_t)m * C_ + n0] = ov;
      }
    }
  }
}

// ---------------------------------------------------------------------------
// Kernel 4: pipelined causal flash attention, 8 WAVES (512 thr), QBLK=256,
// KVBLK=64, no P-LDS. (R17-proven, unchanged.)
// K/V double-buffered, ONE barrier/step, stage-to-regs right after the
// barrier, LDS-write after compute into buf[cur^1]; defer-max rescale;
// K rows staged PERMUTED (row l(g) = g5 g2 g4g3 g1g0) so packed P dwords
// are exactly the PV B-fragments (P never touches LDS); lane-partial l;
// staging role-split (waves 0-3 stage V, waves 4-7 stage K); no skips.
// Grid 512, LPT (qt=7-(j>>3)), head-per-XCD swizzle.
// ---------------------------------------------------------------------------
#define KSTR 72
__global__ __launch_bounds__(512) void attn_kernel(
    const unsigned short* __restrict__ Qg, const unsigned short* __restrict__ Kg,
    const unsigned short* __restrict__ Vg, unsigned short* __restrict__ ctx) {
  __shared__ __align__(16) unsigned short Ks[2][64][KSTR];    // [buf][kv'][d]
  __shared__ __align__(16) unsigned short VTs[2][64][KSTR];   // [buf][d][kv]

  const int tid = threadIdx.x, wid = tid >> 6, lane = tid & 63;
  const int fr = lane & 15, fq = lane >> 4;

  const int bid = blockIdx.x;
  const int xcd = bid & 7, j = bid >> 3;        // j in 0..63
  const int bh = xcd * 8 + (j & 7);             // 8 heads per XCD (L2 locality)
  const int qt = 7 - (j >> 3);                  // q-tile 0..7, longest first
  const int b = bh >> 4, h = bh & 15;
  const size_t base = (size_t)bh * (T_ * D_);

  // Staging roles: waves 0-3 (tid<256) stage V; waves 4-7 stage K.
  const int vc = (tid & 255) >> 5, vr_ = tid & 31;
  const int kt = tid & 255, ksr = kt >> 2, ksc = kt & 3;
  const int kpr = ((ksr >> 5) & 1) * 32 + ((ksr >> 2) & 1) * 16 +
                  ((ksr >> 3) & 3) * 4 + (ksr & 3);
  const unsigned short* Kptr = Kg + base + (size_t)ksr * D_ + ksc * 8;
  const unsigned short* Vptr = Vg + base + (size_t)(2 * vr_) * D_ + vc * 8;

  int4 sa_, sb_;    // staging payload (role-dependent)
  auto stage_load = [&](int kv) {
    if (wid < 4) {  // V role
      const unsigned short* vp = Vptr + (size_t)kv * D_;
      sa_ = *(const int4*)vp;          // kv row 2vr_
      sb_ = *(const int4*)(vp + D_);   // kv row 2vr_+1
    } else {        // K role
      const unsigned short* kp = Kptr + (size_t)kv * D_;
      sa_ = *(const int4*)kp;
      sb_ = *(const int4*)(kp + 32);
    }
  };
  auto stage_write = [&](int nb) {
    if (wid < 4) {  // V: packed kv-pair transpose writes
      const unsigned short* pa = (const unsigned short*)&sa_;
      const unsigned short* pb = (const unsigned short*)&sb_;
#pragma unroll
      for (int i = 0; i < 8; ++i) {
        unsigned w = (unsigned)pa[i] | ((unsigned)pb[i] << 16);
        *(unsigned*)&VTs[nb][vc * 8 + i][2 * vr_] = w;
      }
    } else {        // K: permuted-row b128 writes
      *(int4*)&Ks[nb][kpr][ksc * 8]       = sa_;
      *(int4*)&Ks[nb][kpr][(ksc + 4) * 8] = sb_;
    }
  };

  stage_load(0);
  stage_write(0);           // tile 0 -> buf 0 (visible after first barrier)

  const int qbase = qt * 256;
  const int qrow = qbase + wid * 32;    // wave's first q row

  bf16x8 qf[2][2];          // [subtile][t]
#pragma unroll
  for (int x = 0; x < 2; ++x)
#pragma unroll
    for (int t = 0; t < 2; ++t)
      qf[x][t] = *(const bf16x8*)
          &Qg[base + (size_t)(qrow + 16 * x + fr) * D_ + t * 32 + fq * 8];

  f32x4 acc[2][4] = {};     // [subtile][d-tile]; O^T: q=row+fr, d=dt*16+fq*4+r
  float m_run[2] = {-__builtin_inff(), -__builtin_inff()};
  float l_run[2] = {0.f, 0.f};   // lane-partial; cross-fq reduced at finalize

  const int nsteps = 4 * qt + 4;   // kv tiles of 64: 0 .. qbase+192
  int kv0 = 0;
  for (int s = 0; s < nsteps; ++s) {
    const int  cur = s & 1;
    const bool have_next = (s + 1 < nsteps);

    __syncthreads();                              // buf[cur] ready; buf[cur^1] free
    if (have_next) stage_load(kv0 + 64);          // prefetch to regs (T14)

    // ---- K fragments (shared by both subtiles; data permuted at staging) ----
    bf16x8 kf[8];
#pragma unroll
    for (int nt = 0; nt < 4; ++nt)
#pragma unroll
      for (int t = 0; t < 2; ++t)
        kf[nt * 2 + t] = *(const bf16x8*)&Ks[cur][nt * 16 + fr][t * 32 + fq * 8];

    // ---- per-subtile: S^T = K Q^T, softmax, P packed in registers ----
    bf16x8 pf[2][2];        // [subtile][t] PV B-fragments, lane-local
#pragma unroll
    for (int x = 0; x < 2; ++x) {
      f32x4 sv[4];
      __builtin_amdgcn_s_setprio(1);
#pragma unroll
      for (int nt = 0; nt < 4; ++nt) {
        f32x4 sa = {};
        sa = __builtin_amdgcn_mfma_f32_16x16x32_bf16(kf[nt * 2 + 0], qf[x][0], sa, 0, 0, 0);
        sa = __builtin_amdgcn_mfma_f32_16x16x32_bf16(kf[nt * 2 + 1], qf[x][1], sa, 0, 0, 0);
        sv[nt] = sa;
      }
      __builtin_amdgcn_s_setprio(0);

      const int qrx = qrow + 16 * x;      // subtile's first row (16-aligned)
      float mt = -__builtin_inff();
      if (kv0 + 63 > qrx) {               // tile reaches/passes the diagonal
        const int qi = qrx + fr;
#pragma unroll
        for (int nt = 0; nt < 4; ++nt)
#pragma unroll
          for (int r = 0; r < 4; ++r) {
            int kvi = kv0 + 32 * (nt >> 1) + 8 * fq + 4 * (nt & 1) + r;
            float v = sv[nt][r];
            if (kvi > qi) v = -__builtin_inff();
            sv[nt][r] = v;
            mt = fmaxf(mt, v);
          }
      } else {                            // strictly below diagonal: unmasked
#pragma unroll
        for (int nt = 0; nt < 4; ++nt)
          mt = fmaxf(mt, fmaxf(fmaxf(sv[nt][0], sv[nt][1]),
                               fmaxf(sv[nt][2], sv[nt][3])));
      }
      mt = fmaxf(mt, __shfl_xor(mt, 16));
      mt = fmaxf(mt, __shfl_xor(mt, 32));

      // defer-max: rescale only when the row max grew by > 8 log2-units
      if (__any(mt > m_run[x] + 8.0f)) {
        float mn = fmaxf(m_run[x], mt);   // per-lane: mn==m_run -> c=exp2(0)=1
        float c  = exp2fast(m_run[x] - mn);   // first tile: exp2(-inf)=0
        m_run[x] = mn;
#pragma unroll
        for (int dt = 0; dt < 4; ++dt) acc[x][dt] *= c;
        l_run[x] *= c;
      }

      float lsum = 0.f;
      int pw[8];                          // dwords: pw[(nt>>1)*4 + (nt&1)*2 + w]
#pragma unroll
      for (int nt = 0; nt < 4; ++nt) {
        float p0 = exp2fast(sv[nt][0] - m_run[x]);   // masked -> 0
        float p1 = exp2fast(sv[nt][1] - m_run[x]);
        float p2 = exp2fast(sv[nt][2] - m_run[x]);
        float p3 = exp2fast(sv[nt][3] - m_run[x]);
        lsum += (p0 + p1) + (p2 + p3);
        pw[(nt >> 1) * 4 + (nt & 1) * 2 + 0] = (int)cvt_pk_bf16(p0, p1);
        pw[(nt >> 1) * 4 + (nt & 1) * 2 + 1] = (int)cvt_pk_bf16(p2, p3);
      }
      l_run[x] += lsum;                   // lane-partial (reduced at finalize)

#pragma unroll
      for (int t = 0; t < 2; ++t) {
        int4 v4 = {pw[t * 4 + 0], pw[t * 4 + 1], pw[t * 4 + 2], pw[t * 4 + 3]};
        pf[x][t] = __builtin_bit_cast(bf16x8, v4);
      }
    }

    // ---- O^T += V^T P^T : P straight from registers ----
    __builtin_amdgcn_s_setprio(1);
#pragma unroll
    for (int t = 0; t < 2; ++t)
#pragma unroll
      for (int dt = 0; dt < 4; ++dt) {
        bf16x8 vf = *(const bf16x8*)&VTs[cur][dt * 16 + fr][t * 32 + fq * 8];
        acc[0][dt] = __builtin_amdgcn_mfma_f32_16x16x32_bf16(vf, pf[0][t], acc[0][dt], 0, 0, 0);
        acc[1][dt] = __builtin_amdgcn_mfma_f32_16x16x32_bf16(vf, pf[1][t], acc[1][dt], 0, 0, 0);
      }
    __builtin_amdgcn_s_setprio(0);

    if (have_next) stage_write(cur ^ 1);          // next tile -> other buffer
    kv0 += 64;
  }

  // ---- finalize both subtiles ----
#pragma unroll
  for (int x = 0; x < 2; ++x) {
    float l = l_run[x];
    l += __shfl_xor(l, 16);               // cross-fq reduce
    l += __shfl_xor(l, 32);
    float linv = 1.0f / l;
    unsigned short* orow =
        ctx + (size_t)(b * T_ + qrow + 16 * x + fr) * C_ + h * D_;
#pragma unroll
    for (int dt = 0; dt < 4; ++dt) {
      u16x4 o;
#pragma unroll
      for (int r = 0; r < 4; ++r) o[r] = f2bf(acc[x][dt][r] * linv);
      *(u16x4*)&orow[dt * 16 + fq * 4] = o;
    }
  }
}

// ---------------------------------------------------------------------------
extern "C" void kernel_launch(void* const* d_in, const int* in_sizes, int n_in,
                              void* d_out, int out_size, void* d_ws, size_t ws_size,
                              hipStream_t stream) {
  const float* x  = (const float*)d_in[0];
  // d_in[1] = mask: exactly tril -> causality hardcoded in attn kernel
  const float* Wq = (const float*)d_in[2];
  const float* Wk = (const float*)d_in[3];
  const float* Wv = (const float*)d_in[4];
  const float* Wo = (const float*)d_in[5];
  const float* bo = (const float*)d_in[6];

  // workspace carve (all bf16/ushort elements)
  unsigned short* xb  = (unsigned short*)d_ws;     // 8192*1024
  unsigned short* wqt = xb  + (size_t)M_ * C_;     // [3072][1024] fused QKV W^T
  unsigned short* wot = wqt + (size_t)3 * C_ * C_;
  unsigned short* Qb  = wot + (size_t)C_ * C_;     // (B,H,T,D), then K, then V
  unsigned short* ctxb = xb;                       // alias: x dead after QKV

  conv_x_kernel<<<4096, 256, 0, stream>>>(x, xb);
  conv_wt_kernel<<<dim3(16, 16, 4), 256, 0, stream>>>(Wq, Wk, Wv, Wo, wqt);

  gemm128<0><<<dim3(24, M_ / 128), 256, 0, stream>>>(xb, wqt, Qb, nullptr, C_);

  attn_kernel<<<dim3(512), 512, 0, stream>>>(
      Qb, Qb + (size_t)M_ * C_, Qb + (size_t)2 * M_ * C_, ctxb);

  gemm128<1><<<dim3(8, M_ / 128), 256, 0, stream>>>(ctxb, wot, d_out, bo, C_);
}